// Round 1
// baseline (225.305 us; speedup 1.0000x reference)
//
#include <hip/hip_runtime.h>

// BagOfWords: input [1024, 512] int32 tokens in [0, 50257).
// Output [1024, 50256] float32: per-row histogram, vocab bin 0 dropped.
//
// R5 split design. Rocprof showed the fused kernel's store pipe at ~50%
// duty cycle: 8 lockstep blocks/CU alternate {LDS zero, LDS atomics,
// barrier(vmcnt0 drain), LDS read+cvt, store}, so 205.8 MB of mandatory
// stores took ~75 us instead of the ~31 us the harness's own fill kernel
// proves achievable (6.6 TB/s) on this buffer.
//
//   K1: pure grid-stride float4 zero-fill -- no LDS, no barriers, nothing
//       between stores. Same structure as rocclr fillBufferAligned.
//       Plain stores, NOT nontemporal (R4: nt forces HBM write-through
//       past the MALL, +10 us).
//   K2: 524,288 threads, 1 token each, global f32 atomicAdd into the
//       zeroed output. ~524K atomics total, random over a MALL-resident
//       205.8 MB; 8192 waves hide line-fetch latency; in-row duplicate
//       tokens (~2.6/row expected) are handled by the atomic itself.
//
// The kernel boundary (dispatch-end release fence flushes dirty L2)
// guarantees K1's zeros are visible to K2's device-scope atomics. A fused
// store -> __syncthreads -> atomic design is NOT safe: device-scope
// atomics may execute past the local L2 while the zeros sit dirty in it.

#define BATCH 1024
#define SEQ 512
#define VOCAB 50257
#define OUT_COLS (VOCAB - 1)                       // 50256
#define OUT_FLOATS ((size_t)BATCH * OUT_COLS)      // 51,462,144
#define OUT_F4 (OUT_FLOATS / 4)                    // 12,865,536 (50256 % 4 == 0)

#define ZERO_BLOCKS 2048   // 8 blocks/CU, 32 waves -> full occupancy streaming
#define BLOCK 256

__global__ __launch_bounds__(BLOCK) void bow_zero_kernel(float4* __restrict__ out) {
    size_t i = (size_t)blockIdx.x * BLOCK + threadIdx.x;
    const size_t stride = (size_t)ZERO_BLOCKS * BLOCK;
    const float4 z = make_float4(0.0f, 0.0f, 0.0f, 0.0f);
    for (; i < OUT_F4; i += stride) {
        out[i] = z;   // plain global_store_dwordx4, full-line coalesced
    }
}

__global__ __launch_bounds__(BLOCK) void bow_scatter_kernel(
    const int* __restrict__ tokens, float* __restrict__ out) {
    // One thread per token: 2048 blocks x 256 = 524,288 = BATCH*SEQ exactly.
    const int gid = blockIdx.x * BLOCK + threadIdx.x;
    const int tok = tokens[gid];          // coalesced dword load, 2 MB total
    if (tok != 0) {
        const int b = gid >> 9;           // gid / SEQ
        atomicAdd(out + (size_t)b * OUT_COLS + (tok - 1), 1.0f);
    }
}

extern "C" void kernel_launch(void* const* d_in, const int* in_sizes, int n_in,
                              void* d_out, int out_size, void* d_ws, size_t ws_size,
                              hipStream_t stream) {
    const int* tokens = (const int*)d_in[0];
    float* out = (float*)d_out;

    bow_zero_kernel<<<dim3(ZERO_BLOCKS), dim3(BLOCK), 0, stream>>>((float4*)out);
    bow_scatter_kernel<<<dim3((BATCH * SEQ) / BLOCK), dim3(BLOCK), 0, stream>>>(
        tokens, out);
}

// Round 2
// 195.305 us; speedup vs baseline: 1.1536x; 1.1536x over previous
//
#include <hip/hip_runtime.h>

// BagOfWords: input [1024, 512] int32 tokens in [0, 50257).
// Output [1024, 50256] float32: per-row histogram, vocab bin 0 dropped.
//
// R6: persistent half-row fused design.
//   - R5 lesson: global atomic scatter = ~8 G atomics/s (L2-bank RMW misses
//     serialize) -> 65+ us for 524K atomics. LDS histogram is mandatory.
//   - R0 lesson: per-(row,chunk) blocks with __syncthreads spent ~75 us on
//     205.8 MB of stores (~40% store duty cycle). __syncthreads drains
//     vmcnt(0) -> token-load latency and store drains serialize each block.
//   - This version: 2048 blocks (8/CU, 32 waves/CU; 16 KB LDS each).
//     Block = (row, half): loads the row's 512 tokens ONCE into registers,
//     then loops 6-7 chunks of 4096 cols. Inside the loop only raw
//     s_barrier + lgkmcnt(0) waits (LDS-only) -- global stores are
//     fire-and-forget from registers and stay in flight across barriers,
//     overlapping the next chunk's LDS atomics. Store issue throttles only
//     on vmcnt-queue backpressure, i.e. at memory BW.
//   - Plain stores, NOT nontemporal (R4: nt forces HBM write-through past
//     the MALL, +10 us; out buffer is MALL-resident after the poison fill).
//
// LDS hazard audit (raw barriers):
//   barrier1: wave waits lgkmcnt(0) first -> its ds_add atomics complete.
//   between barrier1/barrier2: each thread ds_reads then ds_writes ZERO to
//     its OWN 4x16B slots (per-wave LDS is in-order; same-address read
//     before write preserved). No cross-thread access in this phase.
//   barrier2: lgkmcnt(0) -> zeros visible before next chunk's atomics.
//   Global stores touch addresses no other thread/block ever accesses.

#define BATCH 1024
#define SEQ 512
#define VOCAB 50257
#define OUT_COLS (VOCAB - 1)   // 50256
#define CHUNK 4096
#define NCHUNK 13              // 12 full + 1104-col tail
#define BLOCK 256

// lgkm-only barrier: does NOT drain global stores (unlike __syncthreads,
// which emits s_waitcnt vmcnt(0) lgkmcnt(0)).
#define LDS_BAR()                                              \
    do {                                                       \
        asm volatile("s_waitcnt lgkmcnt(0)" ::: "memory");     \
        __builtin_amdgcn_s_barrier();                          \
        asm volatile("" ::: "memory");                         \
    } while (0)

__global__ __launch_bounds__(BLOCK) void bow_persistent_kernel(
    const int* __restrict__ tokens, float* __restrict__ out) {
    __shared__ unsigned int hist[CHUNK];  // 16 KB -> 8 blocks/CU

    const int t = threadIdx.x;
    const int b = blockIdx.x >> 1;        // row
    const int h = blockIdx.x & 1;         // which half of the 13 chunks
    const int cbeg = h ? 7 : 0;
    const int cend = h ? NCHUNK : 7;

    const uint4 z4 = make_uint4(0u, 0u, 0u, 0u);
    #pragma unroll
    for (int k = 0; k < 4; ++k)
        *(uint4*)&hist[t * 4 + k * (BLOCK * 4)] = z4;

    // Load this row's 512 tokens once (int2/thread), keep in registers.
    const int2 tk = ((const int2*)(tokens + (size_t)b * SEQ))[t];
    const unsigned int cx = (unsigned int)(tk.x - 1);  // tok==0 -> 0xFFFFFFFF
    const unsigned int cy = (unsigned int)(tk.y - 1);

    LDS_BAR();  // zeros visible; token load already waited on by its use below

    for (int c = cbeg; c < cend; ++c) {
        const unsigned int c0 = (unsigned int)c * CHUNK;

        unsigned int r;
        r = cx - c0;
        if (r < CHUNK) atomicAdd(&hist[r], 1u);
        r = cy - c0;
        if (r < CHUNK) atomicAdd(&hist[r], 1u);

        LDS_BAR();

        // Batched readback (one lgkm wait), then re-zero own slots in place.
        uint4 hreg[4];
        #pragma unroll
        for (int k = 0; k < 4; ++k)
            hreg[k] = *(const uint4*)&hist[t * 4 + k * (BLOCK * 4)];
        #pragma unroll
        for (int k = 0; k < 4; ++k)
            *(uint4*)&hist[t * 4 + k * (BLOCK * 4)] = z4;

        LDS_BAR();

        // Fire-and-forget stores from registers; overlap next chunk's LDS work.
        float* orow = out + (size_t)b * OUT_COLS + c0;
        if (c0 + CHUNK <= (unsigned int)OUT_COLS) {
            #pragma unroll
            for (int k = 0; k < 4; ++k) {
                float4 v = make_float4((float)hreg[k].x, (float)hreg[k].y,
                                       (float)hreg[k].z, (float)hreg[k].w);
                *(float4*)(orow + t * 4 + k * (BLOCK * 4)) = v;
            }
        } else {
            const int ncols = OUT_COLS - (int)c0;  // 1104, multiple of 4
            #pragma unroll
            for (int k = 0; k < 4; ++k) {
                const int i = t * 4 + k * (BLOCK * 4);
                if (i < ncols) {
                    float4 v = make_float4((float)hreg[k].x, (float)hreg[k].y,
                                           (float)hreg[k].z, (float)hreg[k].w);
                    *(float4*)(orow + i) = v;
                }
            }
        }
    }
}

extern "C" void kernel_launch(void* const* d_in, const int* in_sizes, int n_in,
                              void* d_out, int out_size, void* d_ws, size_t ws_size,
                              hipStream_t stream) {
    const int* tokens = (const int*)d_in[0];
    float* out = (float*)d_out;

    bow_persistent_kernel<<<dim3(BATCH * 2), dim3(BLOCK), 0, stream>>>(tokens, out);
}